// Round 6
// baseline (132.306 us; speedup 1.0000x reference)
//
#include <hip/hip_runtime.h>
#include <math.h>
#include <stdint.h>

#define NPTS 8192
#define TOPK 30
#define SLOTS 24            // per-lane private slots; last one = dump
#define USABLE 23
#define BUF2SZ 768
#define SENT 0xFFFFFFFFFFFFFFFFULL

// Exact numpy-order key: (float_bits(D) << 32) | j, numpy association order,
// no fma contraction. Unsigned compare == stable top_k order. (Verified r2-r5.)
__device__ __forceinline__ unsigned long long exact_key(const float* __restrict__ X,
                                                        float xi, float yi, float zi, int j) {
#pragma clang fp contract(off)
    float dx = X[j * 3 + 0] - xi;
    float dy = X[j * 3 + 1] - yi;
    float dz = X[j * 3 + 2] - zi;
    float d2 = dx * dx;
    d2 = d2 + dy * dy;
    d2 = d2 + dz * dz;
    float d = sqrtf(d2 + 1e-6f);
    return ((unsigned long long)__float_as_uint(d) << 32) | (unsigned int)j;
}

__device__ __forceinline__ unsigned long long bcast64(unsigned long long v, int src) {
    return (unsigned long long)__shfl((long long)v, src);
}

// AoS -> SoA so the scan's loads are lane-coalesced (48 -> 16 lines per load).
__global__ __launch_bounds__(256)
void soa_transpose_kernel(const float* __restrict__ X, float* __restrict__ ws) {
    const int i = (int)(blockIdx.x * 256 + threadIdx.x);   // 8192 threads
    ws[i]            = X[i * 3 + 0];
    ws[NPTS + i]     = X[i * 3 + 1];
    ws[2 * NPTS + i] = X[i * 3 + 2];
}

__global__ __launch_bounds__(256)
void knn_topk_kernel(const float* __restrict__ X,
                     const float* __restrict__ ws,    // SoA x|y|z
                     const float* __restrict__ mask,
                     float* __restrict__ out)
{
    __shared__ ushort buf [4][SLOTS * 64];    // 12 KB, per-lane private, slot-major
    __shared__ ushort buf2[4][BUF2SZ + 2];    // 6.2 KB, compacted (+dump)

    const int lane = threadIdx.x & 63;
    const int wv   = threadIdx.x >> 6;
    const int row  = (int)(blockIdx.x << 2) | wv;

    const float xi = X[row * 3 + 0];
    const float yi = X[row * 3 + 1];
    const float zi = X[row * 3 + 2];

    // ---- phase 0: T = 16th smallest of 64 per-lane minima over a 512-point
    // strided sample (stride 16). E[|{q<T}|] ~ 300 +- 75 -> rescans ~0. ----
    float smin = INFINITY;
#pragma unroll
    for (int k = 0; k < 8; ++k) {
        const int j = (lane + 64 * k) * 16;
        const float dx = ws[j] - xi;
        const float dy = ws[NPTS + j] - yi;
        const float dz = ws[2 * NPTS + j] - zi;
        smin = fminf(smin, fmaf(dz, dz, fmaf(dy, dy, dx * dx)));
    }
#pragma unroll
    for (int k = 2; k <= 64; k <<= 1) {
#pragma unroll
        for (int m = k >> 1; m >= 1; m >>= 1) {
            const float p = __shfl_xor(smin, m);
            const bool take_min = (((lane & k) == 0) == ((lane & m) == 0));
            smin = ((smin < p) == take_min) ? smin : p;
        }
    }
    float T = __shfl(smin, 15);

    // ---- phase 1: coalesced fixed-T scan, branchless private-slot append ----
    const float4* xs4 = (const float4*)(ws);
    const float4* ys4 = (const float4*)(ws + NPTS);
    const float4* zs4 = (const float4*)(ws + 2 * NPTS);
    int Cv, off, maxv, valid;
    for (;;) {
        int cnt = 0;
        for (int t = 0; t < NPTS / 256; ++t) {
            const int vi = t * 64 + lane;            // coalesced: 16B lane stride
            const float4 xv = xs4[vi];
            const float4 yv = ys4[vi];
            const float4 zv = zs4[vi];
            const int cbase = t * 256 + (lane << 2);

            const float dx0 = xv.x - xi, dy0 = yv.x - yi, dz0 = zv.x - zi;
            const float dx1 = xv.y - xi, dy1 = yv.y - yi, dz1 = zv.y - zi;
            const float dx2 = xv.z - xi, dy2 = yv.z - yi, dz2 = zv.z - zi;
            const float dx3 = xv.w - xi, dy3 = yv.w - yi, dz3 = zv.w - zi;

            const float q0 = fmaf(dz0, dz0, fmaf(dy0, dy0, dx0 * dx0));
            const float q1 = fmaf(dz1, dz1, fmaf(dy1, dy1, dx1 * dx1));
            const float q2 = fmaf(dz2, dz2, fmaf(dy2, dy2, dx2 * dx2));
            const float q3 = fmaf(dz3, dz3, fmaf(dy3, dy3, dx3 * dx3));

#pragma unroll
            for (int k = 0; k < 4; ++k) {
                const float qk = (k == 0) ? q0 : (k == 1) ? q1 : (k == 2) ? q2 : q3;
                const bool  pk = qk < T;
                const int slot = pk ? ((cnt < USABLE) ? cnt : USABLE) : USABLE;
                buf[wv][slot * 64 + lane] = (ushort)(cbase + k);
                cnt += pk ? 1 : 0;
            }
        }

        valid = (cnt < USABLE) ? cnt : USABLE;
        int s = valid;                               // wave prefix-scan
#pragma unroll
        for (int d = 1; d < 64; d <<= 1) {
            const int n = __shfl_up(s, d);
            if (lane >= d) s += n;
        }
        Cv  = __shfl(s, 63);
        off = s - valid;
        maxv = valid;
#pragma unroll
        for (int d = 32; d; d >>= 1) maxv = max(maxv, __shfl_xor(maxv, d));

        const bool anyover = __ballot(cnt > USABLE) != 0ull;
        if (!anyover && Cv >= 33 && Cv <= BUF2SZ) break;   // wave-uniform
        T = (!anyover && Cv < 33) ? T * 2.0f : T * 0.5f;   // ~0-3 waves/launch
    }

    // ---- compact private regions -> buf2 (within-wave, no barrier) ----
    for (int k = 0; k < maxv; ++k) {
        const ushort e = buf[wv][k * 64 + lane];
        const int dst = (k < valid) ? (off + k) : BUF2SZ;  // BUF2SZ = dump
        buf2[wv][dst] = e;
    }

    // ---- phase 2: exact top-30 (chunk bitonic sort + merge, verified) ----
    unsigned long long list = SENT;
    for (int s0 = 0; s0 < Cv; s0 += 64) {
        const int s = s0 + lane;
        unsigned long long ck = SENT;
        if (s < Cv) ck = exact_key(X, xi, yi, zi, (int)buf2[wv][s]);

#pragma unroll
        for (int k = 2; k <= 64; k <<= 1) {
#pragma unroll
            for (int m = k >> 1; m >= 1; m >>= 1) {
                const unsigned long long p = (unsigned long long)__shfl_xor((long long)ck, m);
                const bool take_min = (((lane & k) == 0) == ((lane & m) == 0));
                ck = ((ck < p) == take_min) ? ck : p;
            }
        }

        const unsigned long long cg = bcast64(ck, 63 - lane);
        unsigned long long v = (lane < TOPK) ? list : cg;
#pragma unroll
        for (int m = 32; m >= 1; m >>= 1) {
            const unsigned long long p = (unsigned long long)__shfl_xor((long long)v, m);
            const bool low = ((lane & m) == 0);
            v = (low == (v < p)) ? v : p;
        }
        list = (lane < TOPK) ? v : SENT;
    }

    // ---- emit ----
    if (lane < TOPK) {
        const int   li = (int)(uint32_t)(list & 0xFFFFFFFFu);
        const float lv = __uint_as_float((uint32_t)(list >> 32));
        const int base = row * TOPK + lane;
        out[base]                   = lv;                    // D_neighbors
        out[NPTS * TOPK + base]     = (float)li;             // E_idx
        out[2 * NPTS * TOPK + base] = mask[row] * mask[li];  // mask_neighbors
    }
}

extern "C" void kernel_launch(void* const* d_in, const int* in_sizes, int n_in,
                              void* d_out, int out_size, void* d_ws, size_t ws_size,
                              hipStream_t stream) {
    const float* X    = (const float*)d_in[0];
    const float* mask = (const float*)d_in[1];
    float* out        = (float*)d_out;
    float* ws         = (float*)d_ws;          // 96 KB SoA scratch

    soa_transpose_kernel<<<dim3(NPTS / 256), dim3(256), 0, stream>>>(X, ws);
    knn_topk_kernel<<<dim3(NPTS / 4), dim3(256), 0, stream>>>(X, ws, mask, out);
}